// Round 1
// baseline (668.538 us; speedup 1.0000x reference)
//
#include <hip/hip_runtime.h>
#include <hip/hip_bf16.h>
#include <math.h>

#define H 1024
#define V 32000
#define L 4096

typedef __bf16 bf16x8 __attribute__((ext_vector_type(8)));
typedef float f32x4 __attribute__((ext_vector_type(4)));

__device__ __forceinline__ unsigned short f32_to_bf16(float f) {
    unsigned int u = __float_as_uint(f);
    unsigned int r = (u + 0x7fffu + ((u >> 16) & 1u)) >> 16;
    return (unsigned short)r;
}

__device__ __forceinline__ float dot4(float4 a, float4 b) {
    return a.x * b.x + a.y * b.y + a.z * b.z + a.w * b.w;
}

__device__ __forceinline__ float wave_reduce(float v) {
    for (int off = 32; off; off >>= 1) v += __shfl_xor(v, off);
    return v;
}

// Kernel 1: convert enc (L*H) and uW (H*H) f32 -> bf16; gather embedding row.
__global__ void prep_kernel(const float* __restrict__ enc,
                            const float* __restrict__ uW,
                            const float* __restrict__ emb,
                            const int* __restrict__ token,
                            unsigned short* __restrict__ enc_bf,
                            unsigned short* __restrict__ u_bf,
                            float* __restrict__ emb_vec) {
    int tid = blockIdx.x * blockDim.x + threadIdx.x;
    int stride = gridDim.x * blockDim.x;
    const int NE = L * H / 4;
    const int NU = H * H / 4;
    for (int i = tid; i < NE; i += stride) {
        float4 f = ((const float4*)enc)[i];
        ushort4 o;
        o.x = f32_to_bf16(f.x); o.y = f32_to_bf16(f.y);
        o.z = f32_to_bf16(f.z); o.w = f32_to_bf16(f.w);
        ((ushort4*)enc_bf)[i] = o;
    }
    for (int i = tid; i < NU; i += stride) {
        float4 f = ((const float4*)uW)[i];
        ushort4 o;
        o.x = f32_to_bf16(f.x); o.y = f32_to_bf16(f.y);
        o.z = f32_to_bf16(f.z); o.w = f32_to_bf16(f.w);
        ((ushort4*)u_bf)[i] = o;
    }
    int t0 = token[0];
    for (int i = tid; i < H; i += stride) emb_vec[i] = emb[(size_t)t0 * H + i];
}

// Kernel 2: wh[j] = h0 . wW[j,:] + wb[j] + ub[j]   (one wave per output j)
__global__ void wh_kernel(const float* __restrict__ h0,
                          const float* __restrict__ wW,
                          const float* __restrict__ wb,
                          const float* __restrict__ ub,
                          float* __restrict__ wh) {
    int wave = (blockIdx.x * blockDim.x + threadIdx.x) >> 6;
    int lane = threadIdx.x & 63;
    if (wave >= H) return;
    const float4* row = (const float4*)(wW + (size_t)wave * H);
    const float4* hv = (const float4*)h0;
    float acc = 0.f;
    for (int i = 0; i < 4; i++) {
        int idx = i * 64 + lane;
        acc += dot4(row[idx], hv[idx]);
    }
    acc = wave_reduce(acc);
    if (lane == 0) wh[wave] = acc + wb[wave] + ub[wave];
}

// Kernel 3: scores[l] = sum_j vW[j] * tanh( (E_bf . U_bf^T)[l,j] + wh[j] )
// MFMA 16x16x32 bf16. Block = 4 waves, each wave owns 16 rows of E.
__global__ __launch_bounds__(256) void scores_kernel(
        const unsigned short* __restrict__ enc_bf,
        const unsigned short* __restrict__ u_bf,
        const float* __restrict__ wh,
        const float* __restrict__ vW,
        float* __restrict__ scores) {
    int wave = threadIdx.x >> 6;
    int lane = threadIdx.x & 63;
    int r0 = blockIdx.x * 64 + wave * 16;
    int mrow = lane & 15;   // row within 16-tile (A) / col within tile (B, C/D)
    int quad = lane >> 4;   // k-quad for A/B, row-quad for C/D
    const unsigned short* arow = enc_bf + (size_t)(r0 + mrow) * H + quad * 8;
    float sacc[4] = {0.f, 0.f, 0.f, 0.f};
    for (int nt = 0; nt < 64; nt++) {
        int j0 = nt * 16;
        const unsigned short* brow = u_bf + (size_t)(j0 + mrow) * H + quad * 8;
        f32x4 acc = {0.f, 0.f, 0.f, 0.f};
#pragma unroll
        for (int kk = 0; kk < 32; kk++) {
            bf16x8 a = *(const bf16x8*)(arow + kk * 32);
            bf16x8 b = *(const bf16x8*)(brow + kk * 32);
            acc = __builtin_amdgcn_mfma_f32_16x16x32_bf16(a, b, acc, 0, 0, 0);
        }
        // C/D layout: col = j0 + (lane&15), row = quad*4 + r
        int jcol = j0 + mrow;
        float vj = vW[jcol];
        float whv = wh[jcol];
#pragma unroll
        for (int r = 0; r < 4; r++) {
            sacc[r] += vj * tanhf(acc[r] + whv);
        }
    }
    // reduce over the 16 columns held by lanes sharing the same quad
#pragma unroll
    for (int r = 0; r < 4; r++) {
        float s = sacc[r];
        s += __shfl_xor(s, 1);
        s += __shfl_xor(s, 2);
        s += __shfl_xor(s, 4);
        s += __shfl_xor(s, 8);
        if (mrow == 0) scores[r0 + quad * 4 + r] = s;
    }
}

// Kernel 4: softmax over L=4096, single block of 1024 threads.
__global__ __launch_bounds__(1024) void softmax_kernel(
        const float* __restrict__ scores,
        float* __restrict__ attn_ws,
        float* __restrict__ attn_out) {
    __shared__ float smax[16];
    __shared__ float ssum[16];
    int tid = threadIdx.x;
    int wid = tid >> 6, lane = tid & 63;
    float4 sv = ((const float4*)scores)[tid];
    float vmax = fmaxf(fmaxf(sv.x, sv.y), fmaxf(sv.z, sv.w));
    for (int off = 32; off; off >>= 1) vmax = fmaxf(vmax, __shfl_xor(vmax, off));
    if (lane == 0) smax[wid] = vmax;
    __syncthreads();
    if (tid == 0) {
        float m = smax[0];
        for (int i = 1; i < 16; i++) m = fmaxf(m, smax[i]);
        smax[0] = m;
    }
    __syncthreads();
    float gmax = smax[0];
    float e0 = expf(sv.x - gmax), e1 = expf(sv.y - gmax);
    float e2 = expf(sv.z - gmax), e3 = expf(sv.w - gmax);
    float s = e0 + e1 + e2 + e3;
    s = wave_reduce(s);
    if (lane == 0) ssum[wid] = s;
    __syncthreads();
    if (tid == 0) {
        float t = 0.f;
        for (int i = 0; i < 16; i++) t += ssum[i];
        ssum[0] = t;
    }
    __syncthreads();
    float inv = 1.0f / ssum[0];
    float4 o = make_float4(e0 * inv, e1 * inv, e2 * inv, e3 * inv);
    ((float4*)attn_ws)[tid] = o;
    ((float4*)attn_out)[tid] = o;
}

// Kernel 5: context[k] = sum_l attn[l] * enc[l,k].  grid (4 col-blocks, 128 l-chunks)
__global__ void context_kernel(const float* __restrict__ enc,
                               const float* __restrict__ attn,
                               float* __restrict__ context) {
    int col = blockIdx.x * 256 + threadIdx.x;
    int l0 = blockIdx.y * 32;
    float acc = 0.f;
    for (int l = l0; l < l0 + 32; l++) acc += attn[l] * enc[(size_t)l * H + col];
    atomicAdd(&context[col], acc);
}

// Kernel 6: x[j] = relu( [context; embedded] . cW[j,:] + cb[j] ), one wave per j.
__global__ void combine_kernel(const float* __restrict__ context,
                               const float* __restrict__ emb_vec,
                               const float* __restrict__ cW,
                               const float* __restrict__ cb,
                               float* __restrict__ xvec) {
    int wave = (blockIdx.x * blockDim.x + threadIdx.x) >> 6;
    int lane = threadIdx.x & 63;
    if (wave >= H) return;
    const float4* row = (const float4*)(cW + (size_t)wave * 2 * H);
    const float4* cv = (const float4*)context;
    const float4* ev = (const float4*)emb_vec;
    float acc = 0.f;
    for (int i = 0; i < 4; i++) {
        int idx = i * 64 + lane;
        acc += dot4(row[idx], cv[idx]);
        acc += dot4(row[256 + idx], ev[idx]);
    }
    acc = wave_reduce(acc);
    if (lane == 0) xvec[wave] = fmaxf(acc + cb[wave], 0.f);
}

// Kernel 7: GRU cell, one wave per hidden unit j (6 dot products of K=1024).
__global__ void gru_kernel(const float* __restrict__ xvec,
                           const float* __restrict__ hprev,
                           const float* __restrict__ w_ih,
                           const float* __restrict__ b_ih,
                           const float* __restrict__ w_hh,
                           const float* __restrict__ b_hh,
                           const float* __restrict__ context,
                           float* __restrict__ hnew_out,   // d_out + V
                           float* __restrict__ ovec) {
    int j = (blockIdx.x * blockDim.x + threadIdx.x) >> 6;
    int lane = threadIdx.x & 63;
    if (j >= H) return;
    const float4* xv = (const float4*)xvec;
    const float4* hv = (const float4*)hprev;
    float a0 = 0.f, a1 = 0.f, a2 = 0.f, a3 = 0.f, a4 = 0.f, a5 = 0.f;
    for (int i = 0; i < 4; i++) {
        int idx = i * 64 + lane;
        float4 x4 = xv[idx], h4 = hv[idx];
        a0 += dot4(((const float4*)(w_ih + (size_t)j * H))[idx], x4);
        a1 += dot4(((const float4*)(w_ih + (size_t)(H + j) * H))[idx], x4);
        a2 += dot4(((const float4*)(w_ih + (size_t)(2 * H + j) * H))[idx], x4);
        a3 += dot4(((const float4*)(w_hh + (size_t)j * H))[idx], h4);
        a4 += dot4(((const float4*)(w_hh + (size_t)(H + j) * H))[idx], h4);
        a5 += dot4(((const float4*)(w_hh + (size_t)(2 * H + j) * H))[idx], h4);
    }
    a0 = wave_reduce(a0); a1 = wave_reduce(a1); a2 = wave_reduce(a2);
    a3 = wave_reduce(a3); a4 = wave_reduce(a4); a5 = wave_reduce(a5);
    if (lane == 0) {
        float ir = a0 + b_ih[j], iz = a1 + b_ih[H + j], inn = a2 + b_ih[2 * H + j];
        float hr = a3 + b_hh[j], hz = a4 + b_hh[H + j], hn = a5 + b_hh[2 * H + j];
        float r = 1.f / (1.f + expf(-(ir + hr)));
        float z = 1.f / (1.f + expf(-(iz + hz)));
        float n = tanhf(inn + r * hn);
        float hp = hprev[j];
        float hval = (1.f - z) * n + z * hp;
        hnew_out[j] = hval;
        ovec[j] = context[j] + hval;
    }
}

// Kernel 8: logits[i] = ovec . outW[i,:] + outb[i], one wave per output row.
__global__ void logits_kernel(const float* __restrict__ ovec,
                              const float* __restrict__ outW,
                              const float* __restrict__ outb,
                              float* __restrict__ out) {
    int i = (blockIdx.x * blockDim.x + threadIdx.x) >> 6;
    int lane = threadIdx.x & 63;
    if (i >= V) return;
    const float4* row = (const float4*)(outW + (size_t)i * H);
    const float4* ov = (const float4*)ovec;
    float acc = 0.f;
    for (int t = 0; t < 4; t++) {
        int idx = t * 64 + lane;
        acc += dot4(row[idx], ov[idx]);
    }
    acc = wave_reduce(acc);
    if (lane == 0) out[i] = acc + outb[i];
}

extern "C" void kernel_launch(void* const* d_in, const int* in_sizes, int n_in,
                              void* d_out, int out_size, void* d_ws, size_t ws_size,
                              hipStream_t stream) {
    const int* token = (const int*)d_in[0];
    const float* hidden = (const float*)d_in[1];   // (1,1,H) == hprev == h0
    const float* enc = (const float*)d_in[2];
    const float* emb = (const float*)d_in[3];
    const float* wW = (const float*)d_in[4];
    const float* wb = (const float*)d_in[5];
    const float* uW = (const float*)d_in[6];
    const float* ub = (const float*)d_in[7];
    const float* vW = (const float*)d_in[8];
    const float* cW = (const float*)d_in[9];
    const float* cb = (const float*)d_in[10];
    const float* w_ih = (const float*)d_in[11];
    const float* b_ih = (const float*)d_in[12];
    const float* w_hh = (const float*)d_in[13];
    const float* b_hh = (const float*)d_in[14];
    const float* outW = (const float*)d_in[15];
    const float* outb = (const float*)d_in[16];
    float* out = (float*)d_out;

    char* ws = (char*)d_ws;
    unsigned short* enc_bf = (unsigned short*)ws;                         // 8 MiB
    unsigned short* u_bf = (unsigned short*)(ws + (size_t)L * H * 2);     // 2 MiB
    float* whv = (float*)(ws + (size_t)L * H * 2 + (size_t)H * H * 2);
    float* emb_vec = whv + H;
    float* scores = emb_vec + H;
    float* attn = scores + L;
    float* context = attn + L;
    float* xvec = context + H;
    float* ovec = xvec + H;

    hipMemsetAsync(context, 0, H * sizeof(float), stream);
    prep_kernel<<<1024, 256, 0, stream>>>(enc, uW, emb, token, enc_bf, u_bf, emb_vec);
    wh_kernel<<<256, 256, 0, stream>>>(hidden, wW, wb, ub, whv);
    scores_kernel<<<64, 256, 0, stream>>>(enc_bf, u_bf, whv, vW, scores);
    softmax_kernel<<<1, 1024, 0, stream>>>(scores, attn, out + V + H);
    context_kernel<<<dim3(4, 128), 256, 0, stream>>>(enc, attn, context);
    combine_kernel<<<256, 256, 0, stream>>>(context, emb_vec, cW, cb, xvec);
    gru_kernel<<<256, 256, 0, stream>>>(xvec, hidden, w_ih, b_ih, w_hh, b_hh,
                                        context, out + V, ovec);
    logits_kernel<<<8000, 256, 0, stream>>>(ovec, outW, outb, out);
}

// Round 2
// 355.933 us; speedup vs baseline: 1.8783x; 1.8783x over previous
//
#include <hip/hip_runtime.h>
#include <hip/hip_bf16.h>
#include <math.h>

#define H 1024
#define V 32000
#define L 4096

typedef __bf16 bf16x8 __attribute__((ext_vector_type(8)));
typedef float f32x4 __attribute__((ext_vector_type(4)));

__device__ __forceinline__ unsigned short f32_to_bf16(float f) {
    unsigned int u = __float_as_uint(f);
    unsigned int r = (u + 0x7fffu + ((u >> 16) & 1u)) >> 16;
    return (unsigned short)r;
}

__device__ __forceinline__ float dot4(float4 a, float4 b) {
    return a.x * b.x + a.y * b.y + a.z * b.z + a.w * b.w;
}

__device__ __forceinline__ float wave_reduce(float v) {
    for (int off = 32; off; off >>= 1) v += __shfl_xor(v, off);
    return v;
}

// Kernel 1: convert enc (L*H) and uW (H*H) f32 -> bf16; gather embedding row.
__global__ void prep_kernel(const float* __restrict__ enc,
                            const float* __restrict__ uW,
                            const float* __restrict__ emb,
                            const int* __restrict__ token,
                            unsigned short* __restrict__ enc_bf,
                            unsigned short* __restrict__ u_bf,
                            float* __restrict__ emb_vec) {
    int tid = blockIdx.x * blockDim.x + threadIdx.x;
    int stride = gridDim.x * blockDim.x;
    const int NE = L * H / 4;
    const int NU = H * H / 4;
    for (int i = tid; i < NE; i += stride) {
        float4 f = ((const float4*)enc)[i];
        ushort4 o;
        o.x = f32_to_bf16(f.x); o.y = f32_to_bf16(f.y);
        o.z = f32_to_bf16(f.z); o.w = f32_to_bf16(f.w);
        ((ushort4*)enc_bf)[i] = o;
    }
    for (int i = tid; i < NU; i += stride) {
        float4 f = ((const float4*)uW)[i];
        ushort4 o;
        o.x = f32_to_bf16(f.x); o.y = f32_to_bf16(f.y);
        o.z = f32_to_bf16(f.z); o.w = f32_to_bf16(f.w);
        ((ushort4*)u_bf)[i] = o;
    }
    int t0 = token[0];
    for (int i = tid; i < H; i += stride) emb_vec[i] = emb[(size_t)t0 * H + i];
}

// Kernel 2: wh[j] = h0 . wW[j,:] + wb[j] + ub[j]   (one wave per output j)
__global__ void wh_kernel(const float* __restrict__ h0,
                          const float* __restrict__ wW,
                          const float* __restrict__ wb,
                          const float* __restrict__ ub,
                          float* __restrict__ wh) {
    int wave = (blockIdx.x * blockDim.x + threadIdx.x) >> 6;
    int lane = threadIdx.x & 63;
    if (wave >= H) return;
    const float4* row = (const float4*)(wW + (size_t)wave * H);
    const float4* hv = (const float4*)h0;
    float acc = 0.f;
    for (int i = 0; i < 4; i++) {
        int idx = i * 64 + lane;
        acc += dot4(row[idx], hv[idx]);
    }
    acc = wave_reduce(acc);
    if (lane == 0) wh[wave] = acc + wb[wave] + ub[wave];
}

// Kernel 3 (v2): LDS-tiled fused scores GEMM.
// Grid (64, 4): 64 row-blocks of M=64, 4 j-chunks of N=256. Block = 4 waves.
// Each wave: 16 rows x 256 j-cols = 16 j-tiles of 16x16, K staged 64 at a time.
// Row pad to 72 bf16 (144 B) spreads fragment reads evenly over 32 banks.
// Output: scores_part[chunk][l] = sum over chunk's 256 j of vj*tanh(S+wh).
#define APITCH 72
__global__ __launch_bounds__(256) void scores_kernel(
        const unsigned short* __restrict__ enc_bf,
        const unsigned short* __restrict__ u_bf,
        const float* __restrict__ wh,
        const float* __restrict__ vW,
        float* __restrict__ scores_part) {
    __shared__ unsigned short Als[64 * APITCH];
    __shared__ unsigned short Bls[256 * APITCH];
    int tid = threadIdx.x;
    int wave = tid >> 6, lane = tid & 63;
    int mrow = lane & 15, quad = lane >> 4;
    int r0 = blockIdx.x * 64;
    int jc0 = blockIdx.y * 256;

    f32x4 acc[16];
#pragma unroll
    for (int i = 0; i < 16; i++) acc[i] = (f32x4){0.f, 0.f, 0.f, 0.f};

    for (int k0 = 0; k0 < H; k0 += 64) {
        // Stage A: 64 rows x 64 k  (512 x 16B chunks, 2 per thread)
#pragma unroll
        for (int c = 0; c < 2; c++) {
            int chunk = c * 256 + tid;
            int row = chunk >> 3, ko = (chunk & 7) * 8;
            uint4 v = *(const uint4*)(enc_bf + (size_t)(r0 + row) * H + k0 + ko);
            *(uint4*)(Als + row * APITCH + ko) = v;
        }
        // Stage B: 256 j x 64 k  (2048 x 16B chunks, 8 per thread)
#pragma unroll
        for (int c = 0; c < 8; c++) {
            int chunk = c * 256 + tid;
            int j = chunk >> 3, ko = (chunk & 7) * 8;
            uint4 v = *(const uint4*)(u_bf + (size_t)(jc0 + j) * H + k0 + ko);
            *(uint4*)(Bls + j * APITCH + ko) = v;
        }
        __syncthreads();

        const unsigned short* abase = Als + (wave * 16 + mrow) * APITCH + quad * 8;
        bf16x8 a0 = *(const bf16x8*)(abase);
        bf16x8 a1 = *(const bf16x8*)(abase + 32);
#pragma unroll
        for (int jt = 0; jt < 16; jt++) {
            const unsigned short* bbase = Bls + (jt * 16 + mrow) * APITCH + quad * 8;
            bf16x8 b0 = *(const bf16x8*)(bbase);
            bf16x8 b1 = *(const bf16x8*)(bbase + 32);
            acc[jt] = __builtin_amdgcn_mfma_f32_16x16x32_bf16(a0, b0, acc[jt], 0, 0, 0);
            acc[jt] = __builtin_amdgcn_mfma_f32_16x16x32_bf16(a1, b1, acc[jt], 0, 0, 0);
        }
        __syncthreads();
    }

    // Epilogue: sacc[r] = sum_j vj * tanh(S[row][j] + wh[j]) over this chunk's j.
    // C/D layout: col = lane&15 (j within tile), row = quad*4 + r.
    float sacc[4] = {0.f, 0.f, 0.f, 0.f};
#pragma unroll
    for (int jt = 0; jt < 16; jt++) {
        int jcol = jc0 + jt * 16 + mrow;
        float vj = vW[jcol];
        float whv = wh[jcol];
#pragma unroll
        for (int r = 0; r < 4; r++) {
            sacc[r] += vj * tanhf(acc[jt][r] + whv);
        }
    }
#pragma unroll
    for (int r = 0; r < 4; r++) {
        float s = sacc[r];
        s += __shfl_xor(s, 1);
        s += __shfl_xor(s, 2);
        s += __shfl_xor(s, 4);
        s += __shfl_xor(s, 8);
        if (mrow == 0)
            scores_part[blockIdx.y * L + r0 + wave * 16 + quad * 4 + r] = s;
    }
}

// Kernel 4: softmax over L=4096 (sums 4 score partials), single 1024-thread block.
__global__ __launch_bounds__(1024) void softmax_kernel(
        const float* __restrict__ scores_part,
        float* __restrict__ attn_ws,
        float* __restrict__ attn_out) {
    __shared__ float smax[16];
    __shared__ float ssum[16];
    int tid = threadIdx.x;
    int wid = tid >> 6, lane = tid & 63;
    float4 sv = ((const float4*)scores_part)[tid];
#pragma unroll
    for (int c = 1; c < 4; c++) {
        float4 p = ((const float4*)(scores_part + c * L))[tid];
        sv.x += p.x; sv.y += p.y; sv.z += p.z; sv.w += p.w;
    }
    float vmax = fmaxf(fmaxf(sv.x, sv.y), fmaxf(sv.z, sv.w));
    for (int off = 32; off; off >>= 1) vmax = fmaxf(vmax, __shfl_xor(vmax, off));
    if (lane == 0) smax[wid] = vmax;
    __syncthreads();
    if (tid == 0) {
        float m = smax[0];
        for (int i = 1; i < 16; i++) m = fmaxf(m, smax[i]);
        smax[0] = m;
    }
    __syncthreads();
    float gmax = smax[0];
    float e0 = expf(sv.x - gmax), e1 = expf(sv.y - gmax);
    float e2 = expf(sv.z - gmax), e3 = expf(sv.w - gmax);
    float s = e0 + e1 + e2 + e3;
    s = wave_reduce(s);
    if (lane == 0) ssum[wid] = s;
    __syncthreads();
    if (tid == 0) {
        float t = 0.f;
        for (int i = 0; i < 16; i++) t += ssum[i];
        ssum[0] = t;
    }
    __syncthreads();
    float inv = 1.0f / ssum[0];
    float4 o = make_float4(e0 * inv, e1 * inv, e2 * inv, e3 * inv);
    ((float4*)attn_ws)[tid] = o;
    ((float4*)attn_out)[tid] = o;
}

// Kernel 5: context[k] = sum_l attn[l] * enc[l,k].  grid (4 col-blocks, 128 l-chunks)
__global__ void context_kernel(const float* __restrict__ enc,
                               const float* __restrict__ attn,
                               float* __restrict__ context) {
    int col = blockIdx.x * 256 + threadIdx.x;
    int l0 = blockIdx.y * 32;
    float acc = 0.f;
    for (int l = l0; l < l0 + 32; l++) acc += attn[l] * enc[(size_t)l * H + col];
    atomicAdd(&context[col], acc);
}

// Kernel 6: x[j] = relu( [context; embedded] . cW[j,:] + cb[j] ), one wave per j.
__global__ void combine_kernel(const float* __restrict__ context,
                               const float* __restrict__ emb_vec,
                               const float* __restrict__ cW,
                               const float* __restrict__ cb,
                               float* __restrict__ xvec) {
    int wave = (blockIdx.x * blockDim.x + threadIdx.x) >> 6;
    int lane = threadIdx.x & 63;
    if (wave >= H) return;
    const float4* row = (const float4*)(cW + (size_t)wave * 2 * H);
    const float4* cv = (const float4*)context;
    const float4* ev = (const float4*)emb_vec;
    float acc = 0.f;
    for (int i = 0; i < 4; i++) {
        int idx = i * 64 + lane;
        acc += dot4(row[idx], cv[idx]);
        acc += dot4(row[256 + idx], ev[idx]);
    }
    acc = wave_reduce(acc);
    if (lane == 0) xvec[wave] = fmaxf(acc + cb[wave], 0.f);
}

// Kernel 7: GRU cell, one wave per hidden unit j (6 dot products of K=1024).
__global__ void gru_kernel(const float* __restrict__ xvec,
                           const float* __restrict__ hprev,
                           const float* __restrict__ w_ih,
                           const float* __restrict__ b_ih,
                           const float* __restrict__ w_hh,
                           const float* __restrict__ b_hh,
                           const float* __restrict__ context,
                           float* __restrict__ hnew_out,   // d_out + V
                           float* __restrict__ ovec) {
    int j = (blockIdx.x * blockDim.x + threadIdx.x) >> 6;
    int lane = threadIdx.x & 63;
    if (j >= H) return;
    const float4* xv = (const float4*)xvec;
    const float4* hv = (const float4*)hprev;
    float a0 = 0.f, a1 = 0.f, a2 = 0.f, a3 = 0.f, a4 = 0.f, a5 = 0.f;
    for (int i = 0; i < 4; i++) {
        int idx = i * 64 + lane;
        float4 x4 = xv[idx], h4 = hv[idx];
        a0 += dot4(((const float4*)(w_ih + (size_t)j * H))[idx], x4);
        a1 += dot4(((const float4*)(w_ih + (size_t)(H + j) * H))[idx], x4);
        a2 += dot4(((const float4*)(w_ih + (size_t)(2 * H + j) * H))[idx], x4);
        a3 += dot4(((const float4*)(w_hh + (size_t)j * H))[idx], h4);
        a4 += dot4(((const float4*)(w_hh + (size_t)(H + j) * H))[idx], h4);
        a5 += dot4(((const float4*)(w_hh + (size_t)(2 * H + j) * H))[idx], h4);
    }
    a0 = wave_reduce(a0); a1 = wave_reduce(a1); a2 = wave_reduce(a2);
    a3 = wave_reduce(a3); a4 = wave_reduce(a4); a5 = wave_reduce(a5);
    if (lane == 0) {
        float ir = a0 + b_ih[j], iz = a1 + b_ih[H + j], inn = a2 + b_ih[2 * H + j];
        float hr = a3 + b_hh[j], hz = a4 + b_hh[H + j], hn = a5 + b_hh[2 * H + j];
        float r = 1.f / (1.f + expf(-(ir + hr)));
        float z = 1.f / (1.f + expf(-(iz + hz)));
        float n = tanhf(inn + r * hn);
        float hp = hprev[j];
        float hval = (1.f - z) * n + z * hp;
        hnew_out[j] = hval;
        ovec[j] = context[j] + hval;
    }
}

// Kernel 8: logits[i] = ovec . outW[i,:] + outb[i], one wave per output row.
__global__ void logits_kernel(const float* __restrict__ ovec,
                              const float* __restrict__ outW,
                              const float* __restrict__ outb,
                              float* __restrict__ out) {
    int i = (blockIdx.x * blockDim.x + threadIdx.x) >> 6;
    int lane = threadIdx.x & 63;
    if (i >= V) return;
    const float4* row = (const float4*)(outW + (size_t)i * H);
    const float4* ov = (const float4*)ovec;
    float acc = 0.f;
    for (int t = 0; t < 4; t++) {
        int idx = t * 64 + lane;
        acc += dot4(row[idx], ov[idx]);
    }
    acc = wave_reduce(acc);
    if (lane == 0) out[i] = acc + outb[i];
}

extern "C" void kernel_launch(void* const* d_in, const int* in_sizes, int n_in,
                              void* d_out, int out_size, void* d_ws, size_t ws_size,
                              hipStream_t stream) {
    const int* token = (const int*)d_in[0];
    const float* hidden = (const float*)d_in[1];   // (1,1,H) == hprev == h0
    const float* enc = (const float*)d_in[2];
    const float* emb = (const float*)d_in[3];
    const float* wW = (const float*)d_in[4];
    const float* wb = (const float*)d_in[5];
    const float* uW = (const float*)d_in[6];
    const float* ub = (const float*)d_in[7];
    const float* vW = (const float*)d_in[8];
    const float* cW = (const float*)d_in[9];
    const float* cb = (const float*)d_in[10];
    const float* w_ih = (const float*)d_in[11];
    const float* b_ih = (const float*)d_in[12];
    const float* w_hh = (const float*)d_in[13];
    const float* b_hh = (const float*)d_in[14];
    const float* outW = (const float*)d_in[15];
    const float* outb = (const float*)d_in[16];
    float* out = (float*)d_out;

    char* ws = (char*)d_ws;
    unsigned short* enc_bf = (unsigned short*)ws;                         // 8 MiB
    unsigned short* u_bf = (unsigned short*)(ws + (size_t)L * H * 2);     // 2 MiB
    float* whv = (float*)(ws + (size_t)L * H * 2 + (size_t)H * H * 2);
    float* emb_vec = whv + H;
    float* scores_part = emb_vec + H;        // 4*L floats
    float* attn = scores_part + 4 * L;       // L
    float* context = attn + L;               // H
    float* xvec = context + H;               // H
    float* ovec = xvec + H;                  // H

    hipMemsetAsync(context, 0, H * sizeof(float), stream);
    prep_kernel<<<1024, 256, 0, stream>>>(enc, uW, emb, token, enc_bf, u_bf, emb_vec);
    wh_kernel<<<256, 256, 0, stream>>>(hidden, wW, wb, ub, whv);
    scores_kernel<<<dim3(64, 4), 256, 0, stream>>>(enc_bf, u_bf, whv, vW, scores_part);
    softmax_kernel<<<1, 1024, 0, stream>>>(scores_part, attn, out + V + H);
    context_kernel<<<dim3(4, 128), 256, 0, stream>>>(enc, attn, context);
    combine_kernel<<<256, 256, 0, stream>>>(context, emb_vec, cW, cb, xvec);
    gru_kernel<<<256, 256, 0, stream>>>(xvec, hidden, w_ih, b_ih, w_hh, b_hh,
                                        context, out + V, ovec);
    logits_kernel<<<8000, 256, 0, stream>>>(ovec, outW, outb, out);
}

// Round 3
// 355.836 us; speedup vs baseline: 1.8788x; 1.0003x over previous
//
#include <hip/hip_runtime.h>
#include <hip/hip_bf16.h>
#include <math.h>

#define H 1024
#define V 32000
#define L 4096

typedef __bf16 bf16x8 __attribute__((ext_vector_type(8)));
typedef float f32x4 __attribute__((ext_vector_type(4)));

__device__ __forceinline__ unsigned short f32_to_bf16(float f) {
    unsigned int u = __float_as_uint(f);
    unsigned int r = (u + 0x7fffu + ((u >> 16) & 1u)) >> 16;
    return (unsigned short)r;
}

__device__ __forceinline__ float dot4(float4 a, float4 b) {
    return a.x * b.x + a.y * b.y + a.z * b.z + a.w * b.w;
}

__device__ __forceinline__ float wave_reduce(float v) {
    for (int off = 32; off; off >>= 1) v += __shfl_xor(v, off);
    return v;
}

// Kernel 1: fused prep (f32->bf16 of enc, uW; embedding gather) + wh GEMV.
// Blocks 0..1023: conversion (grid-stride). Blocks 1024..1279: wh (1024 waves).
__global__ __launch_bounds__(256) void prep_wh_kernel(
        const float* __restrict__ enc,
        const float* __restrict__ uW,
        const float* __restrict__ emb,
        const int* __restrict__ token,
        const float* __restrict__ h0,
        const float* __restrict__ wW,
        const float* __restrict__ wb,
        const float* __restrict__ ub,
        unsigned short* __restrict__ enc_bf,
        unsigned short* __restrict__ u_bf,
        float* __restrict__ emb_vec,
        float* __restrict__ wh) {
    if (blockIdx.x < 1024) {
        int tid = blockIdx.x * 256 + threadIdx.x;
        const int stride = 1024 * 256;
        const int NE = L * H / 4;
        const int NU = H * H / 4;
        for (int i = tid; i < NE; i += stride) {
            float4 f = ((const float4*)enc)[i];
            ushort4 o;
            o.x = f32_to_bf16(f.x); o.y = f32_to_bf16(f.y);
            o.z = f32_to_bf16(f.z); o.w = f32_to_bf16(f.w);
            ((ushort4*)enc_bf)[i] = o;
        }
        for (int i = tid; i < NU; i += stride) {
            float4 f = ((const float4*)uW)[i];
            ushort4 o;
            o.x = f32_to_bf16(f.x); o.y = f32_to_bf16(f.y);
            o.z = f32_to_bf16(f.z); o.w = f32_to_bf16(f.w);
            ((ushort4*)u_bf)[i] = o;
        }
        int t0 = token[0];
        for (int i = tid; i < H; i += stride) emb_vec[i] = emb[(size_t)t0 * H + i];
    } else {
        int wave = ((blockIdx.x - 1024) * 256 + threadIdx.x) >> 6;
        int lane = threadIdx.x & 63;
        const float4* row = (const float4*)(wW + (size_t)wave * H);
        const float4* hv = (const float4*)h0;
        float acc = 0.f;
#pragma unroll
        for (int i = 0; i < 4; i++) {
            int idx = i * 64 + lane;
            acc += dot4(row[idx], hv[idx]);
        }
        acc = wave_reduce(acc);
        if (lane == 0) wh[wave] = acc + wb[wave] + ub[wave];
    }
}

// Kernel 2 (v3): LDS-tiled fused scores GEMM, M=32 x N=128 per block.
// Grid (128, 8). Block = 4 waves in 2x2 (wm rows, wn cols). ~6 blocks/CU.
// Row pitch 72 bf16 (144 B): fragment reads land 2-way per bank (free).
#define APITCH 72
__global__ __launch_bounds__(256) void scores_kernel(
        const unsigned short* __restrict__ enc_bf,
        const unsigned short* __restrict__ u_bf,
        const float* __restrict__ wh,
        const float* __restrict__ vW,
        float* __restrict__ scores_part) {
    __shared__ unsigned short Als[32 * APITCH];
    __shared__ unsigned short Bls[128 * APITCH];
    int tid = threadIdx.x;
    int wave = tid >> 6, lane = tid & 63;
    int wm = wave >> 1, wn = wave & 1;
    int mrow = lane & 15, quad = lane >> 4;
    int r0b = blockIdx.x * 32;
    int jc0b = blockIdx.y * 128;

    f32x4 acc[4];
#pragma unroll
    for (int i = 0; i < 4; i++) acc[i] = (f32x4){0.f, 0.f, 0.f, 0.f};

    for (int k0 = 0; k0 < H; k0 += 64) {
        // Stage A: 32 rows x 64 k = 256 x 16B chunks, 1 per thread.
        {
            int row = tid >> 3, ko = (tid & 7) * 8;
            uint4 v = *(const uint4*)(enc_bf + (size_t)(r0b + row) * H + k0 + ko);
            *(uint4*)(Als + row * APITCH + ko) = v;
        }
        // Stage B: 128 j x 64 k = 1024 x 16B chunks, 4 per thread.
#pragma unroll
        for (int c = 0; c < 4; c++) {
            int chunk = c * 256 + tid;
            int j = chunk >> 3, ko = (chunk & 7) * 8;
            uint4 v = *(const uint4*)(u_bf + (size_t)(jc0b + j) * H + k0 + ko);
            *(uint4*)(Bls + j * APITCH + ko) = v;
        }
        __syncthreads();

        const unsigned short* abase = Als + (wm * 16 + mrow) * APITCH + quad * 8;
        bf16x8 a0 = *(const bf16x8*)(abase);
        bf16x8 a1 = *(const bf16x8*)(abase + 32);
#pragma unroll
        for (int jt = 0; jt < 4; jt++) {
            const unsigned short* bbase =
                Bls + (wn * 64 + jt * 16 + mrow) * APITCH + quad * 8;
            bf16x8 b0 = *(const bf16x8*)(bbase);
            bf16x8 b1 = *(const bf16x8*)(bbase + 32);
            acc[jt] = __builtin_amdgcn_mfma_f32_16x16x32_bf16(a0, b0, acc[jt], 0, 0, 0);
            acc[jt] = __builtin_amdgcn_mfma_f32_16x16x32_bf16(a1, b1, acc[jt], 0, 0, 0);
        }
        __syncthreads();
    }

    // Epilogue: sacc[r] = sum over this block-chunk's 64 j of vj*tanh(S+wh).
    // C/D layout: col = lane&15 (j within tile), row = quad*4 + r.
    float sacc[4] = {0.f, 0.f, 0.f, 0.f};
#pragma unroll
    for (int jt = 0; jt < 4; jt++) {
        int jcol = jc0b + wn * 64 + jt * 16 + mrow;
        float vj = vW[jcol];
        float whv = wh[jcol];
#pragma unroll
        for (int r = 0; r < 4; r++) {
            sacc[r] += vj * tanhf(acc[jt][r] + whv);
        }
    }
    // Reduce over the 16 j-columns (lanes with same quad); then the two wn
    // halves write to different partial slabs (2 per j-chunk-block column).
#pragma unroll
    for (int r = 0; r < 4; r++) {
        float s = sacc[r];
        s += __shfl_xor(s, 1);
        s += __shfl_xor(s, 2);
        s += __shfl_xor(s, 4);
        s += __shfl_xor(s, 8);
        if (mrow == 0)
            scores_part[(blockIdx.y * 2 + wn) * L + r0b + wm * 16 + quad * 4 + r] = s;
    }
}

// Kernel 3: softmax over L=4096 (sums 16 score partials); also zeros context.
__global__ __launch_bounds__(1024) void softmax_kernel(
        const float* __restrict__ scores_part,
        float* __restrict__ attn_ws,
        float* __restrict__ attn_out,
        float* __restrict__ context) {
    __shared__ float smax[16];
    __shared__ float ssum[16];
    int tid = threadIdx.x;
    int wid = tid >> 6, lane = tid & 63;
    context[tid] = 0.f;
    float4 sv = ((const float4*)scores_part)[tid];
#pragma unroll
    for (int c = 1; c < 16; c++) {
        float4 p = ((const float4*)(scores_part + c * L))[tid];
        sv.x += p.x; sv.y += p.y; sv.z += p.z; sv.w += p.w;
    }
    float vmax = fmaxf(fmaxf(sv.x, sv.y), fmaxf(sv.z, sv.w));
    for (int off = 32; off; off >>= 1) vmax = fmaxf(vmax, __shfl_xor(vmax, off));
    if (lane == 0) smax[wid] = vmax;
    __syncthreads();
    if (tid == 0) {
        float m = smax[0];
        for (int i = 1; i < 16; i++) m = fmaxf(m, smax[i]);
        smax[0] = m;
    }
    __syncthreads();
    float gmax = smax[0];
    float e0 = expf(sv.x - gmax), e1 = expf(sv.y - gmax);
    float e2 = expf(sv.z - gmax), e3 = expf(sv.w - gmax);
    float s = e0 + e1 + e2 + e3;
    s = wave_reduce(s);
    if (lane == 0) ssum[wid] = s;
    __syncthreads();
    if (tid == 0) {
        float t = 0.f;
        for (int i = 0; i < 16; i++) t += ssum[i];
        ssum[0] = t;
    }
    __syncthreads();
    float inv = 1.0f / ssum[0];
    float4 o = make_float4(e0 * inv, e1 * inv, e2 * inv, e3 * inv);
    ((float4*)attn_ws)[tid] = o;
    ((float4*)attn_out)[tid] = o;
}

// Kernel 4: context[k] = sum_l attn[l] * enc[l,k].  grid (4 col-blocks, 128 l-chunks)
__global__ void context_kernel(const float* __restrict__ enc,
                               const float* __restrict__ attn,
                               float* __restrict__ context) {
    int col = blockIdx.x * 256 + threadIdx.x;
    int l0 = blockIdx.y * 32;
    float acc = 0.f;
    for (int l = l0; l < l0 + 32; l++) acc += attn[l] * enc[(size_t)l * H + col];
    atomicAdd(&context[col], acc);
}

// Kernel 5: x[j] = relu( [context; embedded] . cW[j,:] + cb[j] ), one wave per j.
__global__ void combine_kernel(const float* __restrict__ context,
                               const float* __restrict__ emb_vec,
                               const float* __restrict__ cW,
                               const float* __restrict__ cb,
                               float* __restrict__ xvec) {
    int wave = (blockIdx.x * blockDim.x + threadIdx.x) >> 6;
    int lane = threadIdx.x & 63;
    if (wave >= H) return;
    const float4* row = (const float4*)(cW + (size_t)wave * 2 * H);
    const float4* cv = (const float4*)context;
    const float4* ev = (const float4*)emb_vec;
    float acc = 0.f;
#pragma unroll
    for (int i = 0; i < 4; i++) {
        int idx = i * 64 + lane;
        acc += dot4(row[idx], cv[idx]);
        acc += dot4(row[256 + idx], ev[idx]);
    }
    acc = wave_reduce(acc);
    if (lane == 0) xvec[wave] = fmaxf(acc + cb[wave], 0.f);
}

// Kernel 6: GRU cell, one wave per hidden unit j (6 dot products of K=1024).
__global__ void gru_kernel(const float* __restrict__ xvec,
                           const float* __restrict__ hprev,
                           const float* __restrict__ w_ih,
                           const float* __restrict__ b_ih,
                           const float* __restrict__ w_hh,
                           const float* __restrict__ b_hh,
                           const float* __restrict__ context,
                           float* __restrict__ hnew_out,   // d_out + V
                           float* __restrict__ ovec) {
    int j = (blockIdx.x * blockDim.x + threadIdx.x) >> 6;
    int lane = threadIdx.x & 63;
    if (j >= H) return;
    const float4* xv = (const float4*)xvec;
    const float4* hv = (const float4*)hprev;
    float a0 = 0.f, a1 = 0.f, a2 = 0.f, a3 = 0.f, a4 = 0.f, a5 = 0.f;
#pragma unroll
    for (int i = 0; i < 4; i++) {
        int idx = i * 64 + lane;
        float4 x4 = xv[idx], h4 = hv[idx];
        a0 += dot4(((const float4*)(w_ih + (size_t)j * H))[idx], x4);
        a1 += dot4(((const float4*)(w_ih + (size_t)(H + j) * H))[idx], x4);
        a2 += dot4(((const float4*)(w_ih + (size_t)(2 * H + j) * H))[idx], x4);
        a3 += dot4(((const float4*)(w_hh + (size_t)j * H))[idx], h4);
        a4 += dot4(((const float4*)(w_hh + (size_t)(H + j) * H))[idx], h4);
        a5 += dot4(((const float4*)(w_hh + (size_t)(2 * H + j) * H))[idx], h4);
    }
    a0 = wave_reduce(a0); a1 = wave_reduce(a1); a2 = wave_reduce(a2);
    a3 = wave_reduce(a3); a4 = wave_reduce(a4); a5 = wave_reduce(a5);
    if (lane == 0) {
        float ir = a0 + b_ih[j], iz = a1 + b_ih[H + j], inn = a2 + b_ih[2 * H + j];
        float hr = a3 + b_hh[j], hz = a4 + b_hh[H + j], hn = a5 + b_hh[2 * H + j];
        float r = 1.f / (1.f + expf(-(ir + hr)));
        float z = 1.f / (1.f + expf(-(iz + hz)));
        float n = tanhf(inn + r * hn);
        float hp = hprev[j];
        float hval = (1.f - z) * n + z * hp;
        hnew_out[j] = hval;
        ovec[j] = context[j] + hval;
    }
}

// Kernel 7: logits GEMV, 2 rows per wave (8 in-flight 16B loads per lane).
__global__ __launch_bounds__(256) void logits_kernel(
        const float* __restrict__ ovec,
        const float* __restrict__ outW,
        const float* __restrict__ outb,
        float* __restrict__ out) {
    int wave = (blockIdx.x * blockDim.x + threadIdx.x) >> 6;
    int lane = threadIdx.x & 63;
    int i0 = wave * 2;
    if (i0 >= V) return;
    const float4* row0 = (const float4*)(outW + (size_t)i0 * H);
    const float4* row1 = (const float4*)(outW + (size_t)(i0 + 1) * H);
    const float4* ov = (const float4*)ovec;
    float acc0 = 0.f, acc1 = 0.f;
#pragma unroll
    for (int t = 0; t < 4; t++) {
        int idx = t * 64 + lane;
        float4 o4 = ov[idx];
        acc0 += dot4(row0[idx], o4);
        acc1 += dot4(row1[idx], o4);
    }
    acc0 = wave_reduce(acc0);
    acc1 = wave_reduce(acc1);
    if (lane == 0) {
        out[i0] = acc0 + outb[i0];
        out[i0 + 1] = acc1 + outb[i0 + 1];
    }
}

extern "C" void kernel_launch(void* const* d_in, const int* in_sizes, int n_in,
                              void* d_out, int out_size, void* d_ws, size_t ws_size,
                              hipStream_t stream) {
    const int* token = (const int*)d_in[0];
    const float* hidden = (const float*)d_in[1];   // (1,1,H) == hprev == h0
    const float* enc = (const float*)d_in[2];
    const float* emb = (const float*)d_in[3];
    const float* wW = (const float*)d_in[4];
    const float* wb = (const float*)d_in[5];
    const float* uW = (const float*)d_in[6];
    const float* ub = (const float*)d_in[7];
    const float* vW = (const float*)d_in[8];
    const float* cW = (const float*)d_in[9];
    const float* cb = (const float*)d_in[10];
    const float* w_ih = (const float*)d_in[11];
    const float* b_ih = (const float*)d_in[12];
    const float* w_hh = (const float*)d_in[13];
    const float* b_hh = (const float*)d_in[14];
    const float* outW = (const float*)d_in[15];
    const float* outb = (const float*)d_in[16];
    float* out = (float*)d_out;

    char* ws = (char*)d_ws;
    unsigned short* enc_bf = (unsigned short*)ws;                         // 8 MiB
    unsigned short* u_bf = (unsigned short*)(ws + (size_t)L * H * 2);     // 2 MiB
    float* whv = (float*)(ws + (size_t)L * H * 2 + (size_t)H * H * 2);
    float* emb_vec = whv + H;
    float* scores_part = emb_vec + H;        // 16*L floats
    float* attn = scores_part + 16 * L;      // L
    float* context = attn + L;               // H
    float* xvec = context + H;               // H
    float* ovec = xvec + H;                  // H

    prep_wh_kernel<<<1280, 256, 0, stream>>>(enc, uW, emb, token, hidden, wW, wb, ub,
                                             enc_bf, u_bf, emb_vec, whv);
    scores_kernel<<<dim3(128, 8), 256, 0, stream>>>(enc_bf, u_bf, whv, vW, scores_part);
    softmax_kernel<<<1, 1024, 0, stream>>>(scores_part, attn, out + V + H, context);
    context_kernel<<<dim3(4, 128), 256, 0, stream>>>(enc, attn, context);
    combine_kernel<<<256, 256, 0, stream>>>(context, emb_vec, cW, cb, xvec);
    gru_kernel<<<256, 256, 0, stream>>>(xvec, hidden, w_ih, b_ih, w_hh, b_hh,
                                        context, out + V, ovec);
    logits_kernel<<<4000, 256, 0, stream>>>(ovec, outW, outb, out);
}

// Round 4
// 343.236 us; speedup vs baseline: 1.9477x; 1.0367x over previous
//
#include <hip/hip_runtime.h>
#include <hip/hip_bf16.h>
#include <math.h>

#define H 1024
#define V 32000
#define L 4096

typedef __bf16 bf16x8 __attribute__((ext_vector_type(8)));
typedef float f32x4 __attribute__((ext_vector_type(4)));

__device__ __forceinline__ unsigned short f32_to_bf16(float f) {
    unsigned int u = __float_as_uint(f);
    unsigned int r = (u + 0x7fffu + ((u >> 16) & 1u)) >> 16;
    return (unsigned short)r;
}

__device__ __forceinline__ float dot4(float4 a, float4 b) {
    return a.x * b.x + a.y * b.y + a.z * b.z + a.w * b.w;
}

__device__ __forceinline__ float wave_reduce(float v) {
    for (int off = 32; off; off >>= 1) v += __shfl_xor(v, off);
    return v;
}

// Kernel 1: fused prep (f32->bf16 of enc, uW; embedding gather) + wh GEMV
// + zeroing of the scores accumulator.
// Blocks 0..1023: conversion (grid-stride). Blocks 1024..1279: wh (1024 waves).
__global__ __launch_bounds__(256) void prep_wh_kernel(
        const float* __restrict__ enc,
        const float* __restrict__ uW,
        const float* __restrict__ emb,
        const int* __restrict__ token,
        const float* __restrict__ h0,
        const float* __restrict__ wW,
        const float* __restrict__ wb,
        const float* __restrict__ ub,
        unsigned short* __restrict__ enc_bf,
        unsigned short* __restrict__ u_bf,
        float* __restrict__ emb_vec,
        float* __restrict__ wh,
        float* __restrict__ scores) {
    if (blockIdx.x < 1024) {
        int tid = blockIdx.x * 256 + threadIdx.x;
        const int stride = 1024 * 256;
        const int NE = L * H / 4;
        const int NU = H * H / 4;
        for (int i = tid; i < NE; i += stride) {
            float4 f = ((const float4*)enc)[i];
            ushort4 o;
            o.x = f32_to_bf16(f.x); o.y = f32_to_bf16(f.y);
            o.z = f32_to_bf16(f.z); o.w = f32_to_bf16(f.w);
            ((ushort4*)enc_bf)[i] = o;
        }
        for (int i = tid; i < NU; i += stride) {
            float4 f = ((const float4*)uW)[i];
            ushort4 o;
            o.x = f32_to_bf16(f.x); o.y = f32_to_bf16(f.y);
            o.z = f32_to_bf16(f.z); o.w = f32_to_bf16(f.w);
            ((ushort4*)u_bf)[i] = o;
        }
        int t0 = token[0];
        for (int i = tid; i < H; i += stride) emb_vec[i] = emb[(size_t)t0 * H + i];
    } else {
        // zero scores (atomicAdd target): first 16 of these 256 blocks
        int z = (blockIdx.x - 1024) * 256 + threadIdx.x;
        if (z < L) scores[z] = 0.f;
        int wave = ((blockIdx.x - 1024) * 256 + threadIdx.x) >> 6;
        int lane = threadIdx.x & 63;
        const float4* row = (const float4*)(wW + (size_t)wave * H);
        const float4* hv = (const float4*)h0;
        float acc = 0.f;
#pragma unroll
        for (int i = 0; i < 4; i++) {
            int idx = i * 64 + lane;
            acc += dot4(row[idx], hv[idx]);
        }
        acc = wave_reduce(acc);
        if (lane == 0) wh[wave] = acc + wb[wave] + ub[wave];
    }
}

// Kernel 2 (v4): LDS-tiled fused scores GEMM, M=64 x N=128 per block.
// Grid (64, 8) = 512 blocks. 4 waves in 2x2; each wave 32 rows x 64 j.
// Partial tanh-weighted sums accumulate into scores[L] via atomicAdd.
// Block (0,0) also zeroes context for the next kernel's atomicAdds.
#define APITCH 72
__global__ __launch_bounds__(256) void scores_kernel(
        const unsigned short* __restrict__ enc_bf,
        const unsigned short* __restrict__ u_bf,
        const float* __restrict__ wh,
        const float* __restrict__ vW,
        float* __restrict__ scores,
        float* __restrict__ context) {
    __shared__ unsigned short Als[64 * APITCH];
    __shared__ unsigned short Bls[128 * APITCH];
    int tid = threadIdx.x;
    if (blockIdx.x == 0 && blockIdx.y == 0) {
        ((float4*)context)[tid] = make_float4(0.f, 0.f, 0.f, 0.f);  // 1024 floats
    }
    int wave = tid >> 6, lane = tid & 63;
    int wm = wave >> 1, wn = wave & 1;
    int mrow = lane & 15, quad = lane >> 4;
    int r0b = blockIdx.x * 64;
    int jc0b = blockIdx.y * 128;

    f32x4 acc[2][4];
#pragma unroll
    for (int mt = 0; mt < 2; mt++)
#pragma unroll
        for (int jt = 0; jt < 4; jt++) acc[mt][jt] = (f32x4){0.f, 0.f, 0.f, 0.f};

    for (int k0 = 0; k0 < H; k0 += 64) {
        // Stage A: 64 rows x 64 k = 512 x 16B chunks, 2 per thread.
#pragma unroll
        for (int c = 0; c < 2; c++) {
            int chunk = c * 256 + tid;
            int row = chunk >> 3, ko = (chunk & 7) * 8;
            *(uint4*)(Als + row * APITCH + ko) =
                *(const uint4*)(enc_bf + (size_t)(r0b + row) * H + k0 + ko);
        }
        // Stage B: 128 j x 64 k = 1024 x 16B chunks, 4 per thread.
#pragma unroll
        for (int c = 0; c < 4; c++) {
            int chunk = c * 256 + tid;
            int j = chunk >> 3, ko = (chunk & 7) * 8;
            *(uint4*)(Bls + j * APITCH + ko) =
                *(const uint4*)(u_bf + (size_t)(jc0b + j) * H + k0 + ko);
        }
        __syncthreads();

        bf16x8 a[2][2];
#pragma unroll
        for (int mt = 0; mt < 2; mt++) {
            const unsigned short* abase =
                Als + (wm * 32 + mt * 16 + mrow) * APITCH + quad * 8;
            a[mt][0] = *(const bf16x8*)(abase);
            a[mt][1] = *(const bf16x8*)(abase + 32);
        }
#pragma unroll
        for (int jt = 0; jt < 4; jt++) {
            const unsigned short* bbase =
                Bls + (wn * 64 + jt * 16 + mrow) * APITCH + quad * 8;
            bf16x8 b0 = *(const bf16x8*)(bbase);
            bf16x8 b1 = *(const bf16x8*)(bbase + 32);
#pragma unroll
            for (int mt = 0; mt < 2; mt++) {
                acc[mt][jt] = __builtin_amdgcn_mfma_f32_16x16x32_bf16(a[mt][0], b0, acc[mt][jt], 0, 0, 0);
                acc[mt][jt] = __builtin_amdgcn_mfma_f32_16x16x32_bf16(a[mt][1], b1, acc[mt][jt], 0, 0, 0);
            }
        }
        __syncthreads();
    }

    // Epilogue: per row, sum vj*tanh(S+wh) over this block's 64 j.
    // C/D layout: col = lane&15 (j), row = quad*4 + r.
    float sacc[2][4] = {{0.f, 0.f, 0.f, 0.f}, {0.f, 0.f, 0.f, 0.f}};
#pragma unroll
    for (int jt = 0; jt < 4; jt++) {
        int jcol = jc0b + wn * 64 + jt * 16 + mrow;
        float vj = vW[jcol];
        float whv = wh[jcol];
#pragma unroll
        for (int mt = 0; mt < 2; mt++)
#pragma unroll
            for (int r = 0; r < 4; r++)
                sacc[mt][r] += vj * tanhf(acc[mt][jt][r] + whv);
    }
#pragma unroll
    for (int mt = 0; mt < 2; mt++)
#pragma unroll
        for (int r = 0; r < 4; r++) {
            float s = sacc[mt][r];
            s += __shfl_xor(s, 1);
            s += __shfl_xor(s, 2);
            s += __shfl_xor(s, 4);
            s += __shfl_xor(s, 8);
            if (mrow == 0)
                atomicAdd(&scores[r0b + wm * 32 + mt * 16 + quad * 4 + r], s);
        }
}

// Kernel 3: fused softmax + context. Grid (4 col-chunks, 128 l-chunks).
// Every block recomputes softmax stats from scores[L] (cheap, deterministic),
// then accumulates its 32-l x 256-col partial of context via atomicAdd.
// Block (0,0) also writes the attn_weights output.
__global__ __launch_bounds__(256) void ctx_softmax_kernel(
        const float* __restrict__ scores,
        const float* __restrict__ enc,
        float* __restrict__ context,
        float* __restrict__ attn_out) {
    __shared__ float smax[4];
    __shared__ float ssum[4];
    __shared__ float attn_l[32];
    int tid = threadIdx.x;
    int wid = tid >> 6, lane = tid & 63;
    // softmax stats over all L (16 values per thread)
    float4 s0 = ((const float4*)scores)[tid];
    float4 s1 = ((const float4*)scores)[256 + tid];
    float4 s2 = ((const float4*)scores)[512 + tid];
    float4 s3 = ((const float4*)scores)[768 + tid];
    float m = fmaxf(fmaxf(fmaxf(s0.x, s0.y), fmaxf(s0.z, s0.w)),
                    fmaxf(fmaxf(s1.x, s1.y), fmaxf(s1.z, s1.w)));
    m = fmaxf(m, fmaxf(fmaxf(s2.x, s2.y), fmaxf(s2.z, s2.w)));
    m = fmaxf(m, fmaxf(fmaxf(s3.x, s3.y), fmaxf(s3.z, s3.w)));
    for (int off = 32; off; off >>= 1) m = fmaxf(m, __shfl_xor(m, off));
    if (lane == 0) smax[wid] = m;
    __syncthreads();
    float gmax = fmaxf(fmaxf(smax[0], smax[1]), fmaxf(smax[2], smax[3]));
    float e = expf(s0.x - gmax) + expf(s0.y - gmax) + expf(s0.z - gmax) + expf(s0.w - gmax)
            + expf(s1.x - gmax) + expf(s1.y - gmax) + expf(s1.z - gmax) + expf(s1.w - gmax)
            + expf(s2.x - gmax) + expf(s2.y - gmax) + expf(s2.z - gmax) + expf(s2.w - gmax)
            + expf(s3.x - gmax) + expf(s3.y - gmax) + expf(s3.z - gmax) + expf(s3.w - gmax);
    e = wave_reduce(e);
    if (lane == 0) ssum[wid] = e;
    __syncthreads();
    float inv = 1.0f / (ssum[0] + ssum[1] + ssum[2] + ssum[3]);

    int l0 = blockIdx.y * 32;
    if (tid < 32) attn_l[tid] = expf(scores[l0 + tid] - gmax) * inv;
    __syncthreads();

    // attn_weights output (block (0,0) only)
    if (blockIdx.x == 0 && blockIdx.y == 0) {
        float4 a0 = make_float4(expf(s0.x - gmax) * inv, expf(s0.y - gmax) * inv,
                                expf(s0.z - gmax) * inv, expf(s0.w - gmax) * inv);
        float4 a1 = make_float4(expf(s1.x - gmax) * inv, expf(s1.y - gmax) * inv,
                                expf(s1.z - gmax) * inv, expf(s1.w - gmax) * inv);
        float4 a2 = make_float4(expf(s2.x - gmax) * inv, expf(s2.y - gmax) * inv,
                                expf(s2.z - gmax) * inv, expf(s2.w - gmax) * inv);
        float4 a3 = make_float4(expf(s3.x - gmax) * inv, expf(s3.y - gmax) * inv,
                                expf(s3.z - gmax) * inv, expf(s3.w - gmax) * inv);
        ((float4*)attn_out)[tid] = a0;
        ((float4*)attn_out)[256 + tid] = a1;
        ((float4*)attn_out)[512 + tid] = a2;
        ((float4*)attn_out)[768 + tid] = a3;
    }

    int col = blockIdx.x * 256 + tid;
    float acc = 0.f;
#pragma unroll 4
    for (int l = 0; l < 32; l++) acc += attn_l[l] * enc[(size_t)(l0 + l) * H + col];
    atomicAdd(&context[col], acc);
}

// Kernel 4: x[j] = relu( [context; embedded] . cW[j,:] + cb[j] ), one wave per j.
__global__ void combine_kernel(const float* __restrict__ context,
                               const float* __restrict__ emb_vec,
                               const float* __restrict__ cW,
                               const float* __restrict__ cb,
                               float* __restrict__ xvec) {
    int wave = (blockIdx.x * blockDim.x + threadIdx.x) >> 6;
    int lane = threadIdx.x & 63;
    if (wave >= H) return;
    const float4* row = (const float4*)(cW + (size_t)wave * 2 * H);
    const float4* cv = (const float4*)context;
    const float4* ev = (const float4*)emb_vec;
    float acc = 0.f;
#pragma unroll
    for (int i = 0; i < 4; i++) {
        int idx = i * 64 + lane;
        acc += dot4(row[idx], cv[idx]);
        acc += dot4(row[256 + idx], ev[idx]);
    }
    acc = wave_reduce(acc);
    if (lane == 0) xvec[wave] = fmaxf(acc + cb[wave], 0.f);
}

// Kernel 5: GRU cell, one wave per hidden unit j (6 dot products of K=1024).
__global__ void gru_kernel(const float* __restrict__ xvec,
                           const float* __restrict__ hprev,
                           const float* __restrict__ w_ih,
                           const float* __restrict__ b_ih,
                           const float* __restrict__ w_hh,
                           const float* __restrict__ b_hh,
                           const float* __restrict__ context,
                           float* __restrict__ hnew_out,   // d_out + V
                           float* __restrict__ ovec) {
    int j = (blockIdx.x * blockDim.x + threadIdx.x) >> 6;
    int lane = threadIdx.x & 63;
    if (j >= H) return;
    const float4* xv = (const float4*)xvec;
    const float4* hv = (const float4*)hprev;
    float a0 = 0.f, a1 = 0.f, a2 = 0.f, a3 = 0.f, a4 = 0.f, a5 = 0.f;
#pragma unroll
    for (int i = 0; i < 4; i++) {
        int idx = i * 64 + lane;
        float4 x4 = xv[idx], h4 = hv[idx];
        a0 += dot4(((const float4*)(w_ih + (size_t)j * H))[idx], x4);
        a1 += dot4(((const float4*)(w_ih + (size_t)(H + j) * H))[idx], x4);
        a2 += dot4(((const float4*)(w_ih + (size_t)(2 * H + j) * H))[idx], x4);
        a3 += dot4(((const float4*)(w_hh + (size_t)j * H))[idx], h4);
        a4 += dot4(((const float4*)(w_hh + (size_t)(H + j) * H))[idx], h4);
        a5 += dot4(((const float4*)(w_hh + (size_t)(2 * H + j) * H))[idx], h4);
    }
    a0 = wave_reduce(a0); a1 = wave_reduce(a1); a2 = wave_reduce(a2);
    a3 = wave_reduce(a3); a4 = wave_reduce(a4); a5 = wave_reduce(a5);
    if (lane == 0) {
        float ir = a0 + b_ih[j], iz = a1 + b_ih[H + j], inn = a2 + b_ih[2 * H + j];
        float hr = a3 + b_hh[j], hz = a4 + b_hh[H + j], hn = a5 + b_hh[2 * H + j];
        float r = 1.f / (1.f + expf(-(ir + hr)));
        float z = 1.f / (1.f + expf(-(iz + hz)));
        float n = tanhf(inn + r * hn);
        float hp = hprev[j];
        float hval = (1.f - z) * n + z * hp;
        hnew_out[j] = hval;
        ovec[j] = context[j] + hval;
    }
}

// Kernel 6: logits GEMV, 2 rows per wave (8 in-flight 16B loads per lane).
__global__ __launch_bounds__(256) void logits_kernel(
        const float* __restrict__ ovec,
        const float* __restrict__ outW,
        const float* __restrict__ outb,
        float* __restrict__ out) {
    int wave = (blockIdx.x * blockDim.x + threadIdx.x) >> 6;
    int lane = threadIdx.x & 63;
    int i0 = wave * 2;
    if (i0 >= V) return;
    const float4* row0 = (const float4*)(outW + (size_t)i0 * H);
    const float4* row1 = (const float4*)(outW + (size_t)(i0 + 1) * H);
    const float4* ov = (const float4*)ovec;
    float acc0 = 0.f, acc1 = 0.f;
#pragma unroll
    for (int t = 0; t < 4; t++) {
        int idx = t * 64 + lane;
        float4 o4 = ov[idx];
        acc0 += dot4(row0[idx], o4);
        acc1 += dot4(row1[idx], o4);
    }
    acc0 = wave_reduce(acc0);
    acc1 = wave_reduce(acc1);
    if (lane == 0) {
        out[i0] = acc0 + outb[i0];
        out[i0 + 1] = acc1 + outb[i0 + 1];
    }
}

extern "C" void kernel_launch(void* const* d_in, const int* in_sizes, int n_in,
                              void* d_out, int out_size, void* d_ws, size_t ws_size,
                              hipStream_t stream) {
    const int* token = (const int*)d_in[0];
    const float* hidden = (const float*)d_in[1];   // (1,1,H) == hprev == h0
    const float* enc = (const float*)d_in[2];
    const float* emb = (const float*)d_in[3];
    const float* wW = (const float*)d_in[4];
    const float* wb = (const float*)d_in[5];
    const float* uW = (const float*)d_in[6];
    const float* ub = (const float*)d_in[7];
    const float* vW = (const float*)d_in[8];
    const float* cW = (const float*)d_in[9];
    const float* cb = (const float*)d_in[10];
    const float* w_ih = (const float*)d_in[11];
    const float* b_ih = (const float*)d_in[12];
    const float* w_hh = (const float*)d_in[13];
    const float* b_hh = (const float*)d_in[14];
    const float* outW = (const float*)d_in[15];
    const float* outb = (const float*)d_in[16];
    float* out = (float*)d_out;

    char* ws = (char*)d_ws;
    unsigned short* enc_bf = (unsigned short*)ws;                         // 8 MiB
    unsigned short* u_bf = (unsigned short*)(ws + (size_t)L * H * 2);     // 2 MiB
    float* whv = (float*)(ws + (size_t)L * H * 2 + (size_t)H * H * 2);
    float* emb_vec = whv + H;
    float* scores = emb_vec + H;             // L floats (atomicAdd target)
    float* context = scores + L;             // H
    float* xvec = context + H;               // H
    float* ovec = xvec + H;                  // H

    prep_wh_kernel<<<1280, 256, 0, stream>>>(enc, uW, emb, token, hidden, wW, wb, ub,
                                             enc_bf, u_bf, emb_vec, whv, scores);
    scores_kernel<<<dim3(64, 8), 256, 0, stream>>>(enc_bf, u_bf, whv, vW, scores, context);
    ctx_softmax_kernel<<<dim3(4, 128), 256, 0, stream>>>(scores, enc, context, out + V + H);
    combine_kernel<<<256, 256, 0, stream>>>(context, emb_vec, cW, cb, xvec);
    gru_kernel<<<256, 256, 0, stream>>>(xvec, hidden, w_ih, b_ih, w_hh, b_hh,
                                        context, out + V, ovec);
    logits_kernel<<<4000, 256, 0, stream>>>(ovec, outW, outb, out);
}

// Round 5
// 340.022 us; speedup vs baseline: 1.9662x; 1.0095x over previous
//
#include <hip/hip_runtime.h>
#include <hip/hip_bf16.h>
#include <math.h>

#define H 1024
#define V 32000
#define L 4096

typedef __bf16 bf16x8 __attribute__((ext_vector_type(8)));
typedef float f32x4 __attribute__((ext_vector_type(4)));

__device__ __forceinline__ unsigned short f32_to_bf16(float f) {
    unsigned int u = __float_as_uint(f);
    unsigned int r = (u + 0x7fffu + ((u >> 16) & 1u)) >> 16;
    return (unsigned short)r;
}

__device__ __forceinline__ float bf16_to_f32(unsigned short s) {
    return __uint_as_float(((unsigned int)s) << 16);
}

__device__ __forceinline__ float dot4(float4 a, float4 b) {
    return a.x * b.x + a.y * b.y + a.z * b.z + a.w * b.w;
}

__device__ __forceinline__ float wave_reduce(float v) {
    for (int off = 32; off; off >>= 1) v += __shfl_xor(v, off);
    return v;
}

// Kernel 1: fused prep (f32->bf16 of enc, uW; embedding gather) + wh GEMV
// + zeroing of the scores accumulator.
// Blocks 0..1023: conversion (grid-stride). Blocks 1024..1279: wh (1024 waves).
__global__ __launch_bounds__(256) void prep_wh_kernel(
        const float* __restrict__ enc,
        const float* __restrict__ uW,
        const float* __restrict__ emb,
        const int* __restrict__ token,
        const float* __restrict__ h0,
        const float* __restrict__ wW,
        const float* __restrict__ wb,
        const float* __restrict__ ub,
        unsigned short* __restrict__ enc_bf,
        unsigned short* __restrict__ u_bf,
        float* __restrict__ emb_vec,
        float* __restrict__ wh,
        float* __restrict__ scores) {
    if (blockIdx.x < 1024) {
        int tid = blockIdx.x * 256 + threadIdx.x;
        const int stride = 1024 * 256;
        const int NE = L * H / 4;
        const int NU = H * H / 4;
        for (int i = tid; i < NE; i += stride) {
            float4 f = ((const float4*)enc)[i];
            ushort4 o;
            o.x = f32_to_bf16(f.x); o.y = f32_to_bf16(f.y);
            o.z = f32_to_bf16(f.z); o.w = f32_to_bf16(f.w);
            ((ushort4*)enc_bf)[i] = o;
        }
        for (int i = tid; i < NU; i += stride) {
            float4 f = ((const float4*)uW)[i];
            ushort4 o;
            o.x = f32_to_bf16(f.x); o.y = f32_to_bf16(f.y);
            o.z = f32_to_bf16(f.z); o.w = f32_to_bf16(f.w);
            ((ushort4*)u_bf)[i] = o;
        }
        int t0 = token[0];
        for (int i = tid; i < H; i += stride) emb_vec[i] = emb[(size_t)t0 * H + i];
    } else {
        // zero scores (atomicAdd target): first 16 of these 256 blocks
        int z = (blockIdx.x - 1024) * 256 + threadIdx.x;
        if (z < L) scores[z] = 0.f;
        int wave = ((blockIdx.x - 1024) * 256 + threadIdx.x) >> 6;
        int lane = threadIdx.x & 63;
        const float4* row = (const float4*)(wW + (size_t)wave * H);
        const float4* hv = (const float4*)h0;
        float acc = 0.f;
#pragma unroll
        for (int i = 0; i < 4; i++) {
            int idx = i * 64 + lane;
            acc += dot4(row[idx], hv[idx]);
        }
        acc = wave_reduce(acc);
        if (lane == 0) wh[wave] = acc + wb[wave] + ub[wave];
    }
}

// Kernel 2 (v4): LDS-tiled fused scores GEMM, M=64 x N=128 per block.
// Grid (64, 8) = 512 blocks. 4 waves in 2x2; each wave 32 rows x 64 j.
// Partial tanh-weighted sums accumulate into scores[L] via atomicAdd.
// Block (0,0) also zeroes context for the next kernel's atomicAdds.
#define APITCH 72
__global__ __launch_bounds__(256) void scores_kernel(
        const unsigned short* __restrict__ enc_bf,
        const unsigned short* __restrict__ u_bf,
        const float* __restrict__ wh,
        const float* __restrict__ vW,
        float* __restrict__ scores,
        float* __restrict__ context) {
    __shared__ unsigned short Als[64 * APITCH];
    __shared__ unsigned short Bls[128 * APITCH];
    int tid = threadIdx.x;
    if (blockIdx.x == 0 && blockIdx.y == 0) {
        ((float4*)context)[tid] = make_float4(0.f, 0.f, 0.f, 0.f);  // 1024 floats
    }
    int wave = tid >> 6, lane = tid & 63;
    int wm = wave >> 1, wn = wave & 1;
    int mrow = lane & 15, quad = lane >> 4;
    int r0b = blockIdx.x * 64;
    int jc0b = blockIdx.y * 128;

    f32x4 acc[2][4];
#pragma unroll
    for (int mt = 0; mt < 2; mt++)
#pragma unroll
        for (int jt = 0; jt < 4; jt++) acc[mt][jt] = (f32x4){0.f, 0.f, 0.f, 0.f};

    for (int k0 = 0; k0 < H; k0 += 64) {
        // Stage A: 64 rows x 64 k = 512 x 16B chunks, 2 per thread.
#pragma unroll
        for (int c = 0; c < 2; c++) {
            int chunk = c * 256 + tid;
            int row = chunk >> 3, ko = (chunk & 7) * 8;
            *(uint4*)(Als + row * APITCH + ko) =
                *(const uint4*)(enc_bf + (size_t)(r0b + row) * H + k0 + ko);
        }
        // Stage B: 128 j x 64 k = 1024 x 16B chunks, 4 per thread.
#pragma unroll
        for (int c = 0; c < 4; c++) {
            int chunk = c * 256 + tid;
            int j = chunk >> 3, ko = (chunk & 7) * 8;
            *(uint4*)(Bls + j * APITCH + ko) =
                *(const uint4*)(u_bf + (size_t)(jc0b + j) * H + k0 + ko);
        }
        __syncthreads();

        bf16x8 a[2][2];
#pragma unroll
        for (int mt = 0; mt < 2; mt++) {
            const unsigned short* abase =
                Als + (wm * 32 + mt * 16 + mrow) * APITCH + quad * 8;
            a[mt][0] = *(const bf16x8*)(abase);
            a[mt][1] = *(const bf16x8*)(abase + 32);
        }
#pragma unroll
        for (int jt = 0; jt < 4; jt++) {
            const unsigned short* bbase =
                Bls + (wn * 64 + jt * 16 + mrow) * APITCH + quad * 8;
            bf16x8 b0 = *(const bf16x8*)(bbase);
            bf16x8 b1 = *(const bf16x8*)(bbase + 32);
#pragma unroll
            for (int mt = 0; mt < 2; mt++) {
                acc[mt][jt] = __builtin_amdgcn_mfma_f32_16x16x32_bf16(a[mt][0], b0, acc[mt][jt], 0, 0, 0);
                acc[mt][jt] = __builtin_amdgcn_mfma_f32_16x16x32_bf16(a[mt][1], b1, acc[mt][jt], 0, 0, 0);
            }
        }
        __syncthreads();
    }

    // Epilogue: per row, sum vj*tanh(S+wh) over this block's 64 j.
    // C/D layout: col = lane&15 (j), row = quad*4 + r.
    float sacc[2][4] = {{0.f, 0.f, 0.f, 0.f}, {0.f, 0.f, 0.f, 0.f}};
#pragma unroll
    for (int jt = 0; jt < 4; jt++) {
        int jcol = jc0b + wn * 64 + jt * 16 + mrow;
        float vj = vW[jcol];
        float whv = wh[jcol];
#pragma unroll
        for (int mt = 0; mt < 2; mt++)
#pragma unroll
            for (int r = 0; r < 4; r++)
                sacc[mt][r] += vj * tanhf(acc[mt][jt][r] + whv);
    }
#pragma unroll
    for (int mt = 0; mt < 2; mt++)
#pragma unroll
        for (int r = 0; r < 4; r++) {
            float s = sacc[mt][r];
            s += __shfl_xor(s, 1);
            s += __shfl_xor(s, 2);
            s += __shfl_xor(s, 4);
            s += __shfl_xor(s, 8);
            if (mrow == 0)
                atomicAdd(&scores[r0b + wm * 32 + mt * 16 + quad * 4 + r], s);
        }
}

// Kernel 3: fused softmax + context. Grid (4 col-chunks, 128 l-chunks).
// Every block recomputes softmax stats from scores[L] (cheap, deterministic),
// then accumulates its 32-l x 256-col partial of context via atomicAdd,
// reading enc in bf16 (enc_bf) to halve the HBM traffic of this pass.
// Block (0,0) also writes the attn_weights output.
__global__ __launch_bounds__(256) void ctx_softmax_kernel(
        const float* __restrict__ scores,
        const unsigned short* __restrict__ enc_bf,
        float* __restrict__ context,
        float* __restrict__ attn_out) {
    __shared__ float smax[4];
    __shared__ float ssum[4];
    __shared__ float attn_l[32];
    int tid = threadIdx.x;
    int wid = tid >> 6, lane = tid & 63;
    // softmax stats over all L (16 values per thread)
    float4 s0 = ((const float4*)scores)[tid];
    float4 s1 = ((const float4*)scores)[256 + tid];
    float4 s2 = ((const float4*)scores)[512 + tid];
    float4 s3 = ((const float4*)scores)[768 + tid];
    float m = fmaxf(fmaxf(fmaxf(s0.x, s0.y), fmaxf(s0.z, s0.w)),
                    fmaxf(fmaxf(s1.x, s1.y), fmaxf(s1.z, s1.w)));
    m = fmaxf(m, fmaxf(fmaxf(s2.x, s2.y), fmaxf(s2.z, s2.w)));
    m = fmaxf(m, fmaxf(fmaxf(s3.x, s3.y), fmaxf(s3.z, s3.w)));
    for (int off = 32; off; off >>= 1) m = fmaxf(m, __shfl_xor(m, off));
    if (lane == 0) smax[wid] = m;
    __syncthreads();
    float gmax = fmaxf(fmaxf(smax[0], smax[1]), fmaxf(smax[2], smax[3]));
    float e = expf(s0.x - gmax) + expf(s0.y - gmax) + expf(s0.z - gmax) + expf(s0.w - gmax)
            + expf(s1.x - gmax) + expf(s1.y - gmax) + expf(s1.z - gmax) + expf(s1.w - gmax)
            + expf(s2.x - gmax) + expf(s2.y - gmax) + expf(s2.z - gmax) + expf(s2.w - gmax)
            + expf(s3.x - gmax) + expf(s3.y - gmax) + expf(s3.z - gmax) + expf(s3.w - gmax);
    e = wave_reduce(e);
    if (lane == 0) ssum[wid] = e;
    __syncthreads();
    float inv = 1.0f / (ssum[0] + ssum[1] + ssum[2] + ssum[3]);

    int l0 = blockIdx.y * 32;
    if (tid < 32) attn_l[tid] = expf(scores[l0 + tid] - gmax) * inv;
    __syncthreads();

    // attn_weights output (block (0,0) only)
    if (blockIdx.x == 0 && blockIdx.y == 0) {
        float4 a0 = make_float4(expf(s0.x - gmax) * inv, expf(s0.y - gmax) * inv,
                                expf(s0.z - gmax) * inv, expf(s0.w - gmax) * inv);
        float4 a1 = make_float4(expf(s1.x - gmax) * inv, expf(s1.y - gmax) * inv,
                                expf(s1.z - gmax) * inv, expf(s1.w - gmax) * inv);
        float4 a2 = make_float4(expf(s2.x - gmax) * inv, expf(s2.y - gmax) * inv,
                                expf(s2.z - gmax) * inv, expf(s2.w - gmax) * inv);
        float4 a3 = make_float4(expf(s3.x - gmax) * inv, expf(s3.y - gmax) * inv,
                                expf(s3.z - gmax) * inv, expf(s3.w - gmax) * inv);
        ((float4*)attn_out)[tid] = a0;
        ((float4*)attn_out)[256 + tid] = a1;
        ((float4*)attn_out)[512 + tid] = a2;
        ((float4*)attn_out)[768 + tid] = a3;
    }

    int col = blockIdx.x * 256 + tid;
    float acc = 0.f;
#pragma unroll 4
    for (int l = 0; l < 32; l++)
        acc += attn_l[l] * bf16_to_f32(enc_bf[(size_t)(l0 + l) * H + col]);
    atomicAdd(&context[col], acc);
}

// Kernel 4: x[j] = relu( [context; embedded] . cW[j,:] + cb[j] ), one wave per j.
__global__ void combine_kernel(const float* __restrict__ context,
                               const float* __restrict__ emb_vec,
                               const float* __restrict__ cW,
                               const float* __restrict__ cb,
                               float* __restrict__ xvec) {
    int wave = (blockIdx.x * blockDim.x + threadIdx.x) >> 6;
    int lane = threadIdx.x & 63;
    if (wave >= H) return;
    const float4* row = (const float4*)(cW + (size_t)wave * 2 * H);
    const float4* cv = (const float4*)context;
    const float4* ev = (const float4*)emb_vec;
    float acc = 0.f;
#pragma unroll
    for (int i = 0; i < 4; i++) {
        int idx = i * 64 + lane;
        acc += dot4(row[idx], cv[idx]);
        acc += dot4(row[256 + idx], ev[idx]);
    }
    acc = wave_reduce(acc);
    if (lane == 0) xvec[wave] = fmaxf(acc + cb[wave], 0.f);
}

// Kernel 5: GRU cell, one wave per hidden unit j (6 dot products of K=1024).
__global__ void gru_kernel(const float* __restrict__ xvec,
                           const float* __restrict__ hprev,
                           const float* __restrict__ w_ih,
                           const float* __restrict__ b_ih,
                           const float* __restrict__ w_hh,
                           const float* __restrict__ b_hh,
                           const float* __restrict__ context,
                           float* __restrict__ hnew_out,   // d_out + V
                           float* __restrict__ ovec) {
    int j = (blockIdx.x * blockDim.x + threadIdx.x) >> 6;
    int lane = threadIdx.x & 63;
    if (j >= H) return;
    const float4* xv = (const float4*)xvec;
    const float4* hv = (const float4*)hprev;
    float a0 = 0.f, a1 = 0.f, a2 = 0.f, a3 = 0.f, a4 = 0.f, a5 = 0.f;
#pragma unroll
    for (int i = 0; i < 4; i++) {
        int idx = i * 64 + lane;
        float4 x4 = xv[idx], h4 = hv[idx];
        a0 += dot4(((const float4*)(w_ih + (size_t)j * H))[idx], x4);
        a1 += dot4(((const float4*)(w_ih + (size_t)(H + j) * H))[idx], x4);
        a2 += dot4(((const float4*)(w_ih + (size_t)(2 * H + j) * H))[idx], x4);
        a3 += dot4(((const float4*)(w_hh + (size_t)j * H))[idx], h4);
        a4 += dot4(((const float4*)(w_hh + (size_t)(H + j) * H))[idx], h4);
        a5 += dot4(((const float4*)(w_hh + (size_t)(2 * H + j) * H))[idx], h4);
    }
    a0 = wave_reduce(a0); a1 = wave_reduce(a1); a2 = wave_reduce(a2);
    a3 = wave_reduce(a3); a4 = wave_reduce(a4); a5 = wave_reduce(a5);
    if (lane == 0) {
        float ir = a0 + b_ih[j], iz = a1 + b_ih[H + j], inn = a2 + b_ih[2 * H + j];
        float hr = a3 + b_hh[j], hz = a4 + b_hh[H + j], hn = a5 + b_hh[2 * H + j];
        float r = 1.f / (1.f + expf(-(ir + hr)));
        float z = 1.f / (1.f + expf(-(iz + hz)));
        float n = tanhf(inn + r * hn);
        float hp = hprev[j];
        float hval = (1.f - z) * n + z * hp;
        hnew_out[j] = hval;
        ovec[j] = context[j] + hval;
    }
}

// Kernel 6: logits GEMV, 2 rows per wave (8 in-flight 16B loads per lane).
__global__ __launch_bounds__(256) void logits_kernel(
        const float* __restrict__ ovec,
        const float* __restrict__ outW,
        const float* __restrict__ outb,
        float* __restrict__ out) {
    int wave = (blockIdx.x * blockDim.x + threadIdx.x) >> 6;
    int lane = threadIdx.x & 63;
    int i0 = wave * 2;
    if (i0 >= V) return;
    const float4* row0 = (const float4*)(outW + (size_t)i0 * H);
    const float4* row1 = (const float4*)(outW + (size_t)(i0 + 1) * H);
    const float4* ov = (const float4*)ovec;
    float acc0 = 0.f, acc1 = 0.f;
#pragma unroll
    for (int t = 0; t < 4; t++) {
        int idx = t * 64 + lane;
        float4 o4 = ov[idx];
        acc0 += dot4(row0[idx], o4);
        acc1 += dot4(row1[idx], o4);
    }
    acc0 = wave_reduce(acc0);
    acc1 = wave_reduce(acc1);
    if (lane == 0) {
        out[i0] = acc0 + outb[i0];
        out[i0 + 1] = acc1 + outb[i0 + 1];
    }
}

extern "C" void kernel_launch(void* const* d_in, const int* in_sizes, int n_in,
                              void* d_out, int out_size, void* d_ws, size_t ws_size,
                              hipStream_t stream) {
    const int* token = (const int*)d_in[0];
    const float* hidden = (const float*)d_in[1];   // (1,1,H) == hprev == h0
    const float* enc = (const float*)d_in[2];
    const float* emb = (const float*)d_in[3];
    const float* wW = (const float*)d_in[4];
    const float* wb = (const float*)d_in[5];
    const float* uW = (const float*)d_in[6];
    const float* ub = (const float*)d_in[7];
    const float* vW = (const float*)d_in[8];
    const float* cW = (const float*)d_in[9];
    const float* cb = (const float*)d_in[10];
    const float* w_ih = (const float*)d_in[11];
    const float* b_ih = (const float*)d_in[12];
    const float* w_hh = (const float*)d_in[13];
    const float* b_hh = (const float*)d_in[14];
    const float* outW = (const float*)d_in[15];
    const float* outb = (const float*)d_in[16];
    float* out = (float*)d_out;

    char* ws = (char*)d_ws;
    unsigned short* enc_bf = (unsigned short*)ws;                         // 8 MiB
    unsigned short* u_bf = (unsigned short*)(ws + (size_t)L * H * 2);     // 2 MiB
    float* whv = (float*)(ws + (size_t)L * H * 2 + (size_t)H * H * 2);
    float* emb_vec = whv + H;
    float* scores = emb_vec + H;             // L floats (atomicAdd target)
    float* context = scores + L;             // H
    float* xvec = context + H;               // H
    float* ovec = xvec + H;                  // H

    prep_wh_kernel<<<1280, 256, 0, stream>>>(enc, uW, emb, token, hidden, wW, wb, ub,
                                             enc_bf, u_bf, emb_vec, whv, scores);
    scores_kernel<<<dim3(64, 8), 256, 0, stream>>>(enc_bf, u_bf, whv, vW, scores, context);
    ctx_softmax_kernel<<<dim3(4, 128), 256, 0, stream>>>(scores, enc_bf, context, out + V + H);
    combine_kernel<<<256, 256, 0, stream>>>(context, emb_vec, cW, cb, xvec);
    gru_kernel<<<256, 256, 0, stream>>>(xvec, hidden, w_ih, b_ih, w_hh, b_hh,
                                        context, out + V, ovec);
    logits_kernel<<<4000, 256, 0, stream>>>(ovec, outW, outb, out);
}